// Round 5
// baseline (498.553 us; speedup 1.0000x reference)
//
#include <hip/hip_runtime.h>

#define D 128
#define BG 8192
#define NPG 64
#define NNODES (BG * NPG)
#define NL 14

#define LBLK 512           // label blocks (16 graphs each)
#define PBLK 2048          // partner blocks (256 rows each)

typedef __attribute__((ext_vector_type(8))) __bf16 bf16x8;
typedef __attribute__((ext_vector_type(16))) float f32x16;

__device__ __forceinline__ unsigned short f2bf(float f) {
  unsigned int u = __float_as_uint(f);
  u += 0x7fffu + ((u >> 16) & 1u);
  return (unsigned short)(u >> 16);
}

// ---------------- kernel 1: cbias (per-graph partner bias) + W fragment prep ----------------
// blocks 0..511: cbias for 16 graphs each.
// block 512: repack Wp1[128:256] (node-block) to bf16 in per-lane MFMA fragment
// order: u16 index e = ((s*4+t)*64 + l)*8 + i  with  k=s*16+(l>>5)*8+i, col=t*32+(l&31).
__global__ __launch_bounds__(256) void k_prep(
    const float* __restrict__ node, const float* __restrict__ glob,
    const float* __restrict__ Wp1, const float* __restrict__ bp1,
    float* __restrict__ ws_cb, unsigned short* __restrict__ ws_wmid)
{
  const int tid = threadIdx.x;
  const int blk = blockIdx.x;
  if (blk == 512) {
    #pragma unroll
    for (int ii = 0; ii < 64; ++ii) {
      int f = tid + ii * 256;            // 16384 elements
      int k = f >> 7, col = f & 127;
      int s = k >> 4, lh = (k >> 3) & 1, i8 = k & 7;
      int t = col >> 5, lr = col & 31;
      int e = ((s * 4 + t) * 64 + lh * 32 + lr) * 8 + i8;
      ws_wmid[e] = f2bf(Wp1[(size_t)(128 + k) * D + col]);
    }
    return;
  }
  __shared__ float in_s[16][256];        // [graph][cur(128) | glob(128)]
  const int g0 = blk * 16;
  #pragma unroll
  for (int i = 0; i < 4; ++i) {
    int idx = tid + i * 256;             // float4 index, 1024 total
    int r = idx >> 6, c4 = idx & 63;
    int g = g0 + r;
    float4 v;
    if (c4 < 32) v = ((const float4*)(node + (size_t)((g + 1) * NPG - 1) * D))[c4];
    else         v = ((const float4*)(glob + (size_t)g * D))[c4 - 32];
    *(float4*)&in_s[r][c4 * 4] = v;
  }
  __syncthreads();
  const int lane = tid & 31, grp = tid >> 5;   // 8 groups x 2 graphs
  float acc[2][4] = {};
  #pragma unroll 2
  for (int k4 = 0; k4 < 64; ++k4) {
    int k = k4 * 4;
    float4 wv[4];
    #pragma unroll
    for (int kk = 0; kk < 4; ++kk) {
      int krow = k + kk;
      int wr = krow < 128 ? krow : krow + 128;   // skip node-block of Wp1
      wv[kk] = *(const float4*)&Wp1[(size_t)wr * D + lane * 4];
    }
    #pragma unroll
    for (int g = 0; g < 2; ++g) {
      float4 iv = *(const float4*)&in_s[grp * 2 + g][k];
      float ie[4] = {iv.x, iv.y, iv.z, iv.w};
      #pragma unroll
      for (int kk = 0; kk < 4; ++kk) {
        acc[g][0] += ie[kk] * wv[kk].x;
        acc[g][1] += ie[kk] * wv[kk].y;
        acc[g][2] += ie[kk] * wv[kk].z;
        acc[g][3] += ie[kk] * wv[kk].w;
      }
    }
  }
  float4 b4 = *(const float4*)&bp1[lane * 4];
  #pragma unroll
  for (int g = 0; g < 2; ++g) {
    float4 o;
    o.x = acc[g][0] + b4.x; o.y = acc[g][1] + b4.y;
    o.z = acc[g][2] + b4.z; o.w = acc[g][3] + b4.w;
    *(float4*)&ws_cb[(size_t)(g0 + grp * 2 + g) * D + lane * 4] = o;
  }
}

// ---------------- kernel 2: fused main ----------------
// blocks [0, LBLK): edge-label MLP, 16 graphs each.
// blocks [LBLK, LBLK+PBLK): partner logits, 256 node rows each (MFMA; A loaded
// global->reg with a fully-hoisted 16-deep load train; W from LDS in fragment order).
__global__ __launch_bounds__(256) void k_main(
    const float* __restrict__ node, const float* __restrict__ glob,
    const unsigned short* __restrict__ wmid,
    const float* __restrict__ ws_cb,
    const float* __restrict__ Wp2, const float* __restrict__ bp2,
    const float* __restrict__ Wl1, const float* __restrict__ bl1,
    const float* __restrict__ Wl2, const float* __restrict__ bl2,
    const float* __restrict__ Wl3, const float* __restrict__ bl3,
    const int* __restrict__ pgi, const int* __restrict__ pni,
    float* __restrict__ out)
{
  __shared__ float smem[8192];           // 32 KB union
  const int tid = threadIdx.x;
  const int blk = blockIdx.x;

  if (blk >= LBLK) {
    // ---------------- partner path ----------------
    unsigned short* wlds = (unsigned short*)smem;
    const int pblk = blk - LBLK;
    const size_t row0 = (size_t)pblk * 256;

    // stage W: 32 KB flat copy (already fragment-ordered in ws)
    {
      const uint4* src = (const uint4*)wmid;
      uint4* dst = (uint4*)smem;
      #pragma unroll
      for (int i = 0; i < 8; ++i) dst[tid + i * 256] = src[tid + i * 256];
    }

    const int l  = tid & 63;
    const int w  = tid >> 6;
    const int lr = l & 31;
    const int lh = l >> 5;
    float wp2r[4];
    #pragma unroll
    for (int t = 0; t < 4; ++t) wp2r[t] = Wp2[t * 32 + lr];
    const float bp2v = bp2[0];

    __syncthreads();

    #pragma unroll 1
    for (int half = 0; half < 2; ++half) {
      const size_t r0 = row0 + half * 128;
      const int graph = pblk * 4 + half * 2 + (w >> 1);   // 64 rows per graph
      float cbr[4];
      #pragma unroll
      for (int t = 0; t < 4; ++t) cbr[t] = ws_cb[(size_t)graph * D + t * 32 + lr];

      // 16-deep hoisted A load train (one 32x128 f32 tile slice per wave)
      const float* Ap = node + (r0 + w * 32 + lr) * D + lh * 8;
      float4 a[16];
      #pragma unroll
      for (int s = 0; s < 8; ++s) {
        a[2 * s]     = *(const float4*)(Ap + s * 16);
        a[2 * s + 1] = *(const float4*)(Ap + s * 16 + 4);
      }

      f32x16 acc[4] = {};
      #pragma unroll
      for (int s = 0; s < 8; ++s) {
        bf16x8 af;
        af[0] = (__bf16)a[2 * s].x;     af[1] = (__bf16)a[2 * s].y;
        af[2] = (__bf16)a[2 * s].z;     af[3] = (__bf16)a[2 * s].w;
        af[4] = (__bf16)a[2 * s + 1].x; af[5] = (__bf16)a[2 * s + 1].y;
        af[6] = (__bf16)a[2 * s + 1].z; af[7] = (__bf16)a[2 * s + 1].w;
        #pragma unroll
        for (int t = 0; t < 4; ++t) {
          bf16x8 wf = *(const bf16x8*)&wlds[(size_t)((s * 4 + t) * 64 + l) * 8];
          acc[t] = __builtin_amdgcn_mfma_f32_32x32x16_bf16(af, wf, acc[t], 0, 0, 0);
        }
      }

      // epilogue: logit[row] = sum_col relu(S+cb)*wp2 (+bp2)
      float partial[16];
      #pragma unroll
      for (int r = 0; r < 16; ++r) partial[r] = 0.f;
      #pragma unroll
      for (int t = 0; t < 4; ++t)
        #pragma unroll
        for (int r = 0; r < 16; ++r) {
          float v = acc[t][r] + cbr[t];
          v = v > 0.f ? v : 0.f;
          partial[r] += v * wp2r[t];
        }
      #pragma unroll
      for (int m = 1; m < 32; m <<= 1)
        #pragma unroll
        for (int r = 0; r < 16; ++r) partial[r] += __shfl_xor(partial[r], m, 64);
      // C/D layout: col=lane&31, row=(r&3)+8*(r>>2)+4*(lane>>5)
      #pragma unroll
      for (int r = 0; r < 16; ++r) {
        if (lr == r) {
          int lrow = w * 32 + (r & 3) + 8 * (r >> 2) + 4 * lh;
          out[r0 + lrow] = partial[r] + bp2v;
        }
      }
    }
    return;
  }

  // ---------------- label path: 16 graphs/block ----------------
  float (*in_s)[384] = (float (*)[384])smem;              // 24 KB
  float (*h1_s)[128] = (float (*)[128])(smem + 16 * 384); // 8 KB
  const int b0 = blk * 16;
  #pragma unroll
  for (int i = 0; i < 6; ++i) {
    int idx = tid + i * 256;             // float4 index, 1536 total
    int r = idx / 96, c4 = idx % 96;
    int b = b0 + r;
    int pg = pgi[b];
    int seg = c4 >> 5, o4 = c4 & 31;
    const float* src;
    if (seg == 0)      src = node + (size_t)((pg + 1) * NPG - 1) * D;
    else if (seg == 1) src = node + (size_t)pni[b] * D;
    else               src = glob + (size_t)pg * D;
    *(float4*)&in_s[r][c4 * 4] = ((const float4*)src)[o4];
  }
  __syncthreads();
  const int lane = tid & 31, grp = tid >> 5;   // 8 groups x 2 graphs
  { // layer 1: [16x384]@[384x128] + relu
    float acc[2][4] = {};
    #pragma unroll 2
    for (int k4 = 0; k4 < 96; ++k4) {
      int k = k4 * 4;
      float4 wv[4];
      #pragma unroll
      for (int kk = 0; kk < 4; ++kk)
        wv[kk] = *(const float4*)&Wl1[(size_t)(k + kk) * D + lane * 4];
      #pragma unroll
      for (int g = 0; g < 2; ++g) {
        float4 iv = *(const float4*)&in_s[grp * 2 + g][k];
        float ie[4] = {iv.x, iv.y, iv.z, iv.w};
        #pragma unroll
        for (int kk = 0; kk < 4; ++kk) {
          acc[g][0] += ie[kk] * wv[kk].x; acc[g][1] += ie[kk] * wv[kk].y;
          acc[g][2] += ie[kk] * wv[kk].z; acc[g][3] += ie[kk] * wv[kk].w;
        }
      }
    }
    float4 b4 = *(const float4*)&bl1[lane * 4];
    #pragma unroll
    for (int g = 0; g < 2; ++g) {
      float4 o;
      o.x = fmaxf(acc[g][0] + b4.x, 0.f); o.y = fmaxf(acc[g][1] + b4.y, 0.f);
      o.z = fmaxf(acc[g][2] + b4.z, 0.f); o.w = fmaxf(acc[g][3] + b4.w, 0.f);
      *(float4*)&h1_s[grp * 2 + g][lane * 4] = o;
    }
  }
  __syncthreads();                        // h1 done; all in_s reads complete
  float* h2_s = &smem[0];                 // 16*128 floats, aliases in_s (in_s dead)
  { // layer 2: [16x128]@[128x128] + relu
    float acc[2][4] = {};
    #pragma unroll 2
    for (int k4 = 0; k4 < 32; ++k4) {
      int k = k4 * 4;
      float4 wv[4];
      #pragma unroll
      for (int kk = 0; kk < 4; ++kk)
        wv[kk] = *(const float4*)&Wl2[(size_t)(k + kk) * D + lane * 4];
      #pragma unroll
      for (int g = 0; g < 2; ++g) {
        float4 iv = *(const float4*)&h1_s[grp * 2 + g][k];
        float ie[4] = {iv.x, iv.y, iv.z, iv.w};
        #pragma unroll
        for (int kk = 0; kk < 4; ++kk) {
          acc[g][0] += ie[kk] * wv[kk].x; acc[g][1] += ie[kk] * wv[kk].y;
          acc[g][2] += ie[kk] * wv[kk].z; acc[g][3] += ie[kk] * wv[kk].w;
        }
      }
    }
    float4 b4 = *(const float4*)&bl2[lane * 4];
    #pragma unroll
    for (int g = 0; g < 2; ++g) {
      float4 o;
      o.x = fmaxf(acc[g][0] + b4.x, 0.f); o.y = fmaxf(acc[g][1] + b4.y, 0.f);
      o.z = fmaxf(acc[g][2] + b4.z, 0.f); o.w = fmaxf(acc[g][3] + b4.w, 0.f);
      *(float4*)&h2_s[(size_t)(grp * 2 + g) * 128 + lane * 4] = o;
    }
  }
  __syncthreads();
  { // layer 3: [16x128]@[128x14]
    int j = tid & 15, g2 = tid >> 4;     // 16 groups x 1 graph
    if (j < NL) {
      float acc2 = 0.f;
      #pragma unroll 2
      for (int k4 = 0; k4 < 32; ++k4) {
        int k = k4 * 4;
        float wv[4];
        #pragma unroll
        for (int kk = 0; kk < 4; ++kk) wv[kk] = Wl3[(size_t)(k + kk) * NL + j];
        float4 iv = *(const float4*)&h2_s[(size_t)g2 * 128 + k];
        acc2 += iv.x * wv[0] + iv.y * wv[1] + iv.z * wv[2] + iv.w * wv[3];
      }
      out[(size_t)NNODES + (size_t)(b0 + g2) * NL + j] = acc2 + bl3[j];
    }
  }
}

extern "C" void kernel_launch(void* const* d_in, const int* in_sizes, int n_in,
                              void* d_out, int out_size, void* d_ws, size_t ws_size,
                              hipStream_t stream) {
  const float* node = (const float*)d_in[0];
  const float* glob = (const float*)d_in[1];
  const float* Wp1  = (const float*)d_in[2];
  const float* bp1  = (const float*)d_in[3];
  const float* Wp2  = (const float*)d_in[4];
  const float* bp2  = (const float*)d_in[5];
  const float* Wl1  = (const float*)d_in[6];
  const float* bl1  = (const float*)d_in[7];
  const float* Wl2  = (const float*)d_in[8];
  const float* bl2  = (const float*)d_in[9];
  const float* Wl3  = (const float*)d_in[10];
  const float* bl3  = (const float*)d_in[11];
  const int* pgi = (const int*)d_in[12];
  const int* pni = (const int*)d_in[13];
  float* out = (float*)d_out;

  float* ws_cb = (float*)d_ws;                                        // 4 MB
  unsigned short* ws_wmid =
      (unsigned short*)((char*)d_ws + (size_t)BG * D * sizeof(float)); // 32 KB

  hipLaunchKernelGGL(k_prep, dim3(513), dim3(256), 0, stream,
                     node, glob, Wp1, bp1, ws_cb, ws_wmid);
  hipLaunchKernelGGL(k_main, dim3(LBLK + PBLK), dim3(256), 0, stream,
                     node, glob, ws_wmid, ws_cb, Wp2, bp2,
                     Wl1, bl1, Wl2, bl2, Wl3, bl3, pgi, pni, out);
}